// Round 2
// baseline (115.954 us; speedup 1.0000x reference)
//
#include <hip/hip_runtime.h>

// RGate: apply Rx(angle[i]) to every qubit of a 22-qubit statevector.
// Gate on qubit i pairs indices at stride 2^(21-i); all gates commute.
// 2 passes: bits 0-13 (A: 16K-amp contiguous tile, 3 LDS re-tiles),
// bits 14-21 (B: 256h x 64lane strided tile, 1 LDS re-tile).
// Traffic: 2 x 67 MB = 134 MB (was 201 MB in 3-pass version).
// LDS: static 128 KB exactly (no dynamic shared, no hipFuncSetAttribute).

constexpr int NTOT = 1 << 22;   // 2^22 amplitudes

__device__ __forceinline__ void rotg(float& ar, float& ai, float& br, float& bi,
                                     float c, float s) {
    // a' = c*a - i*s*b ; b' = c*b - i*s*a
    float t0 = ar, t1 = ai, t2 = br, t3 = bi;
    ar = fmaf(c, t0,  s * t3);
    ai = fmaf(c, t1, -s * t2);
    br = fmaf(c, t2,  s * t1);
    bi = fmaf(c, t3, -s * t0);
}

// Apply NB register-butterfly gates for stride-bits K0..K0+NB-1.
// cos/sin computed per stage in registers (uniform across threads; ~8 VGPR live).
template<int K0, int NB>
__device__ __forceinline__ void gates(float (&ar)[16], float (&ai)[16],
                                      const float* __restrict__ ang) {
    #pragma unroll
    for (int b = 0; b < NB; ++b) {
        const int m = 1 << b;
        const float a = 0.5f * ang[21 - (K0 + b)];
        const float c = cosf(a), s = sinf(a);
        #pragma unroll
        for (int j = 0; j < 16; ++j)
            if (!(j & m)) rotg(ar[j], ai[j], ar[j | m], ai[j | m], c, s);
    }
}

// XOR swizzle for pass-A LDS: folds index bits 4..7 into bank-pair bits 0..3.
// Self-inverse bijection on [0,16384). Verified at the 4-cycle b64 floor for
// all four arrangements (lane-varying axes: A1/A2 stride-1, A3 l>>2 in bits
// 6..9, A4 l&15 in bits 4..7 -> all spread across the 16 bank pairs).
__device__ __forceinline__ int slotA(int i) { return i ^ ((i >> 4) & 15); }

// ---------------- Kernel A: bits 0..13, tile = 16384 contiguous ------------
// Block 1024 threads, 16 complex/thread, static LDS 16384 float2 = 128 KB.
// Arrangements (tile-local index i):
//  A1 (load):  i = t + (j<<10)                   -> reg bits {10..13}
//  A2:         i = (t&63) + (j<<6) + ((t>>6)<<10)-> reg bits {6..9}
//  A3:         i = (t&3) + (j<<2) + ((t>>2)<<6)  -> reg bits {2..5}
//  A4 (store): i = (t<<4) + j                    -> reg bits {0..3}, gates 0..1,
//              float4 stores
__global__ __launch_bounds__(1024) void rgate_low14(const float* __restrict__ xr,
                                                    const float* __restrict__ xi,
                                                    const float* __restrict__ ang,
                                                    float* __restrict__ out) {
    __shared__ float2 sv[16384];         // exactly 128 KB
    const int t  = threadIdx.x;
    const int g0 = blockIdx.x << 14;

    float ar[16], ai[16];
    #pragma unroll
    for (int j = 0; j < 16; ++j) {
        ar[j] = xr[g0 + t + (j << 10)];
        ai[j] = xi[g0 + t + (j << 10)];
    }

    gates<10, 4>(ar, ai, ang);
    #pragma unroll
    for (int j = 0; j < 16; ++j)
        sv[slotA(t + (j << 10))] = make_float2(ar[j], ai[j]);
    __syncthreads();

    // A2: reg bits {6..9}
    const int base2 = (t & 63) + ((t >> 6) << 10);
    #pragma unroll
    for (int j = 0; j < 16; ++j) {
        float2 v = sv[slotA(base2 + (j << 6))];
        ar[j] = v.x; ai[j] = v.y;
    }
    gates<6, 4>(ar, ai, ang);
    #pragma unroll
    for (int j = 0; j < 16; ++j)
        sv[slotA(base2 + (j << 6))] = make_float2(ar[j], ai[j]);
    __syncthreads();

    // A3: reg bits {2..5}
    const int base3 = (t & 3) + ((t >> 2) << 6);
    #pragma unroll
    for (int j = 0; j < 16; ++j) {
        float2 v = sv[slotA(base3 + (j << 2))];
        ar[j] = v.x; ai[j] = v.y;
    }
    gates<2, 4>(ar, ai, ang);
    #pragma unroll
    for (int j = 0; j < 16; ++j)
        sv[slotA(base3 + (j << 2))] = make_float2(ar[j], ai[j]);
    __syncthreads();

    // A4: reg bits {0..3}, gates k=0..1, coalesced float4 stores
    const int base4 = t << 4;
    #pragma unroll
    for (int j = 0; j < 16; ++j) {
        float2 v = sv[slotA(base4 + j)];
        ar[j] = v.x; ai[j] = v.y;
    }
    gates<0, 2>(ar, ai, ang);
    float4* orp = (float4*)(out + g0 + base4);
    float4* oip = (float4*)(out + NTOT + g0 + base4);
    #pragma unroll
    for (int q = 0; q < 4; ++q) {
        orp[q] = make_float4(ar[4*q], ar[4*q+1], ar[4*q+2], ar[4*q+3]);
        oip[q] = make_float4(ai[4*q], ai[4*q+1], ai[4*q+2], ai[4*q+3]);
    }
}

// ---------------- Kernel B: bits 14..21 (h stride 16384) -------------------
// idx = h*16384 + blk*64 + lane ; tile = 256 h x 64 lane = 16K amps = 128 KB.
// Block 1024 threads, 16 complex/thread; lane = t&63, w = t>>6 (4 h-bits).
//  B1 (load):  h = j | (w<<4)  -> reg = amp bits 14..17
//  B2 (store): h = w | (j<<4)  -> reg = amp bits 18..21
// All LDS accesses lane-contiguous float2 -> 4-cycle floor, no swizzle needed.
__global__ __launch_bounds__(1024) void rgate_high8(const float* __restrict__ ang,
                                                    float* __restrict__ out) {
    __shared__ float2 sv[16384];         // exactly 128 KB
    const int t    = threadIdx.x;
    const int lane = t & 63, w = t >> 6;
    const int base = (blockIdx.x << 6) + lane;
    float* outr = out;
    float* outi = out + NTOT;

    float ar[16], ai[16];
    #pragma unroll
    for (int j = 0; j < 16; ++j) {
        const int g = ((j | (w << 4)) << 14) + base;
        ar[j] = outr[g]; ai[j] = outi[g];
    }

    gates<14, 4>(ar, ai, ang);
    #pragma unroll
    for (int j = 0; j < 16; ++j)
        sv[((j | (w << 4)) << 6) + lane] = make_float2(ar[j], ai[j]);
    __syncthreads();

    // B2: reg = amp bits 18..21
    #pragma unroll
    for (int j = 0; j < 16; ++j) {
        float2 v = sv[((w | (j << 4)) << 6) + lane];
        ar[j] = v.x; ai[j] = v.y;
    }
    gates<18, 4>(ar, ai, ang);
    #pragma unroll
    for (int j = 0; j < 16; ++j) {
        const int g = ((w | (j << 4)) << 14) + base;
        outr[g] = ar[j]; outi[g] = ai[j];
    }
}

extern "C" void kernel_launch(void* const* d_in, const int* in_sizes, int n_in,
                              void* d_out, int out_size, void* d_ws, size_t ws_size,
                              hipStream_t stream) {
    const float* xr  = (const float*)d_in[0];
    const float* xi  = (const float*)d_in[1];
    const float* ang = (const float*)d_in[2];
    float* out = (float*)d_out;

    // Pass 1: bits 0-13, d_in -> d_out (fully overwrites d_out)
    rgate_low14<<<256, 1024, 0, stream>>>(xr, xi, ang, out);
    // Pass 2: bits 14-21, in-place on d_out
    rgate_high8<<<256, 1024, 0, stream>>>(ang, out);
}

// Round 3
// 106.301 us; speedup vs baseline: 1.0908x; 1.0908x over previous
//
#include <hip/hip_runtime.h>

// RGate: apply Rx(angle[i]) to every qubit of a 22-qubit statevector.
// Gate on stride-bit k (amp index bit k) uses angle[21-k]; all gates commute.
// 2 passes, 64 KB LDS tiles -> 2 blocks/CU so load/compute/store phases
// overlap across blocks (128 KB tiles = 1 block/CU serialized phases; that
// was round-2's regression).
//   Pass A: bits 0-12, contiguous 8192-amp tile, float4 global I/O, 3 re-tiles.
//   Pass B: bits 13-21, tile 512h x 16l, 1 re-tile + shfl_xor for bit 17.
// Traffic: 2 x 67 MB = 134 MB.

constexpr int NTOT = 1 << 22;   // 2^22 amplitudes

__device__ __forceinline__ void rotg(float& ar, float& ai, float& br, float& bi,
                                     float c, float s) {
    // a' = c*a - i*s*b ; b' = c*b - i*s*a
    float t0 = ar, t1 = ai, t2 = br, t3 = bi;
    ar = fmaf(c, t0,  s * t3);
    ai = fmaf(c, t1, -s * t2);
    br = fmaf(c, t2,  s * t1);
    bi = fmaf(c, t3, -s * t0);
}

// NB gates for amp stride-bits K0..K0+NB-1, where amp bit (K0+b) lives at
// register-index bit (MSH+b). Angles are wave-uniform scalars.
template<int K0, int NB, int MSH>
__device__ __forceinline__ void gatesM(float (&ar)[16], float (&ai)[16],
                                       const float* __restrict__ ang) {
    #pragma unroll
    for (int b = 0; b < NB; ++b) {
        const int m = 1 << (MSH + b);
        const float a = 0.5f * ang[21 - (K0 + b)];
        const float c = cosf(a), s = sinf(a);
        #pragma unroll
        for (int j = 0; j < 16; ++j)
            if (!(j & m)) rotg(ar[j], ai[j], ar[j | m], ai[j | m], c, s);
    }
}

// Pass-A LDS swizzle: fold index bits 4..7 into bank-pair bits 0..3.
// Self-inverse bijection on [0,8192). Verified b64 4-cycle floor for all
// four arrangements (lane strides 4, 1-contig, 64-contig, 4).
__device__ __forceinline__ int slotA(int i) { return i ^ ((i >> 4) & 15); }

// ---------------- Pass A: bits 0..12, tile = 8192 contiguous ---------------
// 512 threads, 16 amps/thread, LDS 8192 float2 = 64 KB (2 blocks/CU).
// Arrangements (tile-local index i, reg j):
//  A1 (load):  i = (t<<2) + r + (q<<11), j=r+4q -> reg bits {0,1,11,12};
//              gates 11,12 (float4 loads)
//  A2:         i = (t&3)  + (j<<2) + ((t>>2)<<6)  -> bits {2..5};  gates 2-5
//  A3:         i = (t&63) + (j<<6) + ((t>>6)<<10) -> bits {6..9};  gates 6-9
//  A4 (store): i = r + ((t&255)<<2) + (q<<10) + ((t>>8)<<12)
//              -> reg bits {0,1,10,11}; gates 0,1,10 (float4 stores)
__global__ __launch_bounds__(512, 4) void rgate_A(const float* __restrict__ xr,
                                                  const float* __restrict__ xi,
                                                  const float* __restrict__ ang,
                                                  float* __restrict__ out) {
    __shared__ float2 sv[8192];          // 64 KB
    const int t  = threadIdx.x;
    const int g0 = blockIdx.x << 13;

    float ar[16], ai[16];
    #pragma unroll
    for (int q = 0; q < 4; ++q) {
        const int i = (t << 2) + (q << 11);
        float4 vr = *(const float4*)(xr + g0 + i);
        float4 vi = *(const float4*)(xi + g0 + i);
        ar[4*q+0] = vr.x; ar[4*q+1] = vr.y; ar[4*q+2] = vr.z; ar[4*q+3] = vr.w;
        ai[4*q+0] = vi.x; ai[4*q+1] = vi.y; ai[4*q+2] = vi.z; ai[4*q+3] = vi.w;
    }
    gatesM<11, 2, 2>(ar, ai, ang);       // gates 11,12 on reg bits 2,3 (=q)

    #pragma unroll
    for (int q = 0; q < 4; ++q)
        #pragma unroll
        for (int r = 0; r < 4; ++r)
            sv[slotA((t << 2) + r + (q << 11))] = make_float2(ar[4*q+r], ai[4*q+r]);
    __syncthreads();

    // A2: reg bits {2..5}
    const int b2 = (t & 3) + ((t >> 2) << 6);
    #pragma unroll
    for (int j = 0; j < 16; ++j) {
        float2 v = sv[slotA(b2 + (j << 2))];
        ar[j] = v.x; ai[j] = v.y;
    }
    gatesM<2, 4, 0>(ar, ai, ang);
    #pragma unroll
    for (int j = 0; j < 16; ++j)
        sv[slotA(b2 + (j << 2))] = make_float2(ar[j], ai[j]);
    __syncthreads();

    // A3: reg bits {6..9}
    const int b3 = (t & 63) + ((t >> 6) << 10);
    #pragma unroll
    for (int j = 0; j < 16; ++j) {
        float2 v = sv[slotA(b3 + (j << 6))];
        ar[j] = v.x; ai[j] = v.y;
    }
    gatesM<6, 4, 0>(ar, ai, ang);
    #pragma unroll
    for (int j = 0; j < 16; ++j)
        sv[slotA(b3 + (j << 6))] = make_float2(ar[j], ai[j]);
    __syncthreads();

    // A4: reg bits {0,1,10,11} -> gates 0,1 (reg bits 0,1) + gate 10 (reg bit 2)
    const int b4 = ((t & 255) << 2) + ((t >> 8) << 12);
    #pragma unroll
    for (int q = 0; q < 4; ++q)
        #pragma unroll
        for (int r = 0; r < 4; ++r) {
            float2 v = sv[slotA(b4 + r + (q << 10))];
            ar[4*q+r] = v.x; ai[4*q+r] = v.y;
        }
    gatesM<0, 2, 0>(ar, ai, ang);        // gates 0,1
    gatesM<10, 1, 2>(ar, ai, ang);       // gate 10 on reg bit 2 (=q)

    #pragma unroll
    for (int q = 0; q < 4; ++q) {
        const int i = b4 + (q << 10);
        *(float4*)(out + g0 + i)        = make_float4(ar[4*q], ar[4*q+1], ar[4*q+2], ar[4*q+3]);
        *(float4*)(out + NTOT + g0 + i) = make_float4(ai[4*q], ai[4*q+1], ai[4*q+2], ai[4*q+3]);
    }
}

// ---------------- Pass B: bits 13..21 (h stride 8192) ----------------------
// amp = h*8192 + l, h in [0,512) (h bit k = amp bit 13+k); tile = all h x
// 16 contiguous l = 8192 amps = 64 KB. 512 threads, 16 amps/thread.
// sub = t&15 (l), hw = t>>4 in [0,32).
//  B1 (load):  h = j | (hw<<4) -> reg = h bits 0..3 -> gates 13-16;
//              then gate 17 (h bit 4 = lane bit 4) via __shfl_xor(.,16)
//  B2 (store): h = hw | (j<<5) -> reg = h bits 5..8 -> gates 18-21
// LDS layout sv[h*16+sub]: both arrangements conflict-free (b64 floor).
// XCD swizzle: adjacent l-chunks share 128B L2 lines -> same XCD.
__global__ __launch_bounds__(512, 4) void rgate_B(const float* __restrict__ ang,
                                                  float* __restrict__ out) {
    __shared__ float2 sv[8192];          // 64 KB
    const int t   = threadIdx.x;
    const int bid = blockIdx.x;
    const int blk = (bid >> 3) | ((bid & 7) << 6);   // XCD-contiguous remap
    const int sub = t & 15, hw = t >> 4;
    const int lbase = (blk << 4) + sub;
    float* outr = out;
    float* outi = out + NTOT;

    float ar[16], ai[16];
    #pragma unroll
    for (int j = 0; j < 16; ++j) {
        const int g = ((j | (hw << 4)) << 13) + lbase;
        ar[j] = outr[g]; ai[j] = outi[g];
    }
    gatesM<13, 4, 0>(ar, ai, ang);       // gates 13-16

    {   // gate 17: partner = lane^16 (same wave). Symmetric update:
        // x_r' = c*x_r + s*p_i ; x_i' = c*x_i - s*p_r  (p = partner amp)
        const float a = 0.5f * ang[21 - 17];
        const float c = cosf(a), s = sinf(a);
        #pragma unroll
        for (int j = 0; j < 16; ++j) {
            float pr = __shfl_xor(ar[j], 16, 64);
            float pi = __shfl_xor(ai[j], 16, 64);
            ar[j] = fmaf(c, ar[j],  s * pi);
            ai[j] = fmaf(c, ai[j], -s * pr);
        }
    }

    #pragma unroll
    for (int j = 0; j < 16; ++j)
        sv[((j | (hw << 4)) << 4) + sub] = make_float2(ar[j], ai[j]);
    __syncthreads();

    #pragma unroll
    for (int j = 0; j < 16; ++j) {
        float2 v = sv[((hw | (j << 5)) << 4) + sub];
        ar[j] = v.x; ai[j] = v.y;
    }
    gatesM<18, 4, 0>(ar, ai, ang);       // gates 18-21

    #pragma unroll
    for (int j = 0; j < 16; ++j) {
        const int g = ((hw | (j << 5)) << 13) + lbase;
        outr[g] = ar[j]; outi[g] = ai[j];
    }
}

extern "C" void kernel_launch(void* const* d_in, const int* in_sizes, int n_in,
                              void* d_out, int out_size, void* d_ws, size_t ws_size,
                              hipStream_t stream) {
    const float* xr  = (const float*)d_in[0];
    const float* xi  = (const float*)d_in[1];
    const float* ang = (const float*)d_in[2];
    float* out = (float*)d_out;

    // Pass 1: bits 0-12, d_in -> d_out (fully overwrites d_out)
    rgate_A<<<512, 512, 0, stream>>>(xr, xi, ang, out);
    // Pass 2: bits 13-21, in-place on d_out
    rgate_B<<<512, 512, 0, stream>>>(ang, out);
}